// Round 10
// baseline (95.256 us; speedup 1.0000x reference)
//
#include <hip/hip_runtime.h>
#include <hip/hip_bf16.h>

#define N_NODES 50000
#define N_EDGES 600000
#define DIM 128
#define CAP 64            // slots per node; P(deg>=64) ~ 1.6e-28 for Poisson(12)

typedef __attribute__((ext_vector_type(8))) short bf16x8;
typedef __attribute__((ext_vector_type(4))) float floatx4;

// ---------------- prep: Wt[n][k] = bf16(W[k][n]); also zero cnt ----------------
__global__ __launch_bounds__(256) void k_prep(const float* __restrict__ W,
                                              ushort* __restrict__ Wt,
                                              int4* __restrict__ cnt4) {
    int b = blockIdx.x;
    if (b < 16) {
        int idx = (b * 256 + threadIdx.x) * 4;
        float4 v = *(const float4*)(W + idx);
        int k = idx >> 7, n = idx & 127;
        Wt[(size_t)(n + 0) * DIM + k] = __bfloat16_as_ushort(__float2bfloat16(v.x));
        Wt[(size_t)(n + 1) * DIM + k] = __bfloat16_as_ushort(__float2bfloat16(v.y));
        Wt[(size_t)(n + 2) * DIM + k] = __bfloat16_as_ushort(__float2bfloat16(v.z));
        Wt[(size_t)(n + 3) * DIM + k] = __bfloat16_as_ushort(__float2bfloat16(v.w));
    } else {
        int i = (b - 16) * 256 + threadIdx.x;
        if (i < N_NODES / 4) cnt4[i] = make_int4(0, 0, 0, 0);
    }
}

// ---------------- direct bucket fill (light: no LDS, low VGPR, full TLP) ------
__global__ __launch_bounds__(256) void k_fill_direct(
        const int* __restrict__ esrc,
        const int* __restrict__ edst,
        const float* __restrict__ ew,
        int* __restrict__ cnt,
        int2* __restrict__ slots) {
    int e = blockIdx.x * blockDim.x + threadIdx.x;
    if (e >= N_EDGES) return;
    int d = edst[e];
    int pos = atomicAdd(&cnt[d], 1);
    if (pos < CAP)
        slots[(size_t)d * CAP + pos] = make_int2(esrc[e], __float_as_int(ew[e]));
}

// ---------------- MFMA GEMM, no LDS: Y = bf16(X @ W), 64 rows/block ----------
// Swapped-operand MFMA (A = W fragment from global/L2, B = X fragment from
// registers) so each lane holds 4 consecutive output cols -> ushort4 stores.
// Layouts (16x16x32 bf16): A row=lane&15 -> Wt row ct*16+m, k=(lane>>4)*8+j;
// B col=lane&15 -> X row wr+m, same k; D col=m, row=q*4+r -> Y[wr+m][ct*16+q*4+r].
__global__ __launch_bounds__(256) void gemm_mfma2(
        const float* __restrict__ X,
        const ushort* __restrict__ Wt,
        ushort* __restrict__ Y) {
    int t = threadIdx.x;
    int w = t >> 6, l = t & 63;
    int wr = blockIdx.x * 64 + w * 16;
    int m = l & 15, q = l >> 4;
    int rowA = wr + m;
    if (rowA >= N_NODES) rowA = N_NODES - 1;      // clamp loads; stores guarded
    const float* xp = X + (size_t)rowA * DIM + q * 8;

    // issue all 8 X float4 loads up front (one latency stall, not four)
    float4 xv[8];
#pragma unroll
    for (int kk = 0; kk < 4; ++kk) {
        xv[2 * kk]     = *(const float4*)(xp + kk * 32);
        xv[2 * kk + 1] = *(const float4*)(xp + kk * 32 + 4);
    }

    // convert to 4 bf16x8 B-fragments
    bf16x8 xf[4];
#pragma unroll
    for (int kk = 0; kk < 4; ++kk) {
        float4 x0 = xv[2 * kk], x1 = xv[2 * kk + 1];
        bf16x8 f;
        f[0] = (short)__bfloat16_as_ushort(__float2bfloat16(x0.x));
        f[1] = (short)__bfloat16_as_ushort(__float2bfloat16(x0.y));
        f[2] = (short)__bfloat16_as_ushort(__float2bfloat16(x0.z));
        f[3] = (short)__bfloat16_as_ushort(__float2bfloat16(x0.w));
        f[4] = (short)__bfloat16_as_ushort(__float2bfloat16(x1.x));
        f[5] = (short)__bfloat16_as_ushort(__float2bfloat16(x1.y));
        f[6] = (short)__bfloat16_as_ushort(__float2bfloat16(x1.z));
        f[7] = (short)__bfloat16_as_ushort(__float2bfloat16(x1.w));
        xf[kk] = f;
    }

    // A-fragments streamed from Wt (32 KB total, L1/L2-resident, shared by all waves)
    const ushort* wp = Wt + (size_t)m * DIM + q * 8;

    floatx4 acc[8];
#pragma unroll
    for (int ct = 0; ct < 8; ++ct)
        acc[ct] = (floatx4){0.f, 0.f, 0.f, 0.f};

#pragma unroll
    for (int ct = 0; ct < 8; ++ct) {
#pragma unroll
        for (int kk = 0; kk < 4; ++kk) {
            bf16x8 wf = *(const bf16x8*)(wp + (size_t)(ct * 16) * DIM + kk * 32);
            acc[ct] = __builtin_amdgcn_mfma_f32_16x16x32_bf16(wf, xf[kk], acc[ct], 0, 0, 0);
        }
    }

    int row = wr + m;
    if (row < N_NODES) {
        ushort* yp = Y + (size_t)row * DIM + q * 4;
#pragma unroll
        for (int ct = 0; ct < 8; ++ct) {
            ushort4 o;
            o.x = __bfloat16_as_ushort(__float2bfloat16(acc[ct][0]));
            o.y = __bfloat16_as_ushort(__float2bfloat16(acc[ct][1]));
            o.z = __bfloat16_as_ushort(__float2bfloat16(acc[ct][2]));
            o.w = __bfloat16_as_ushort(__float2bfloat16(acc[ct][3]));
            *(ushort4*)(yp + ct * 16) = o;
        }
    }
}

// ---------------- gather from bf16 Y over padded buckets ----------------
__device__ __forceinline__ float bf_lo(unsigned u) {
    return __uint_as_float(u << 16);
}
__device__ __forceinline__ float bf_hi(unsigned u) {
    return __uint_as_float(u & 0xFFFF0000u);
}

#define ACC8(A, W, Y4)                                   \
    A[0] += (W) * bf_lo((Y4).x); A[1] += (W) * bf_hi((Y4).x); \
    A[2] += (W) * bf_lo((Y4).y); A[3] += (W) * bf_hi((Y4).y); \
    A[4] += (W) * bf_lo((Y4).z); A[5] += (W) * bf_hi((Y4).z); \
    A[6] += (W) * bf_lo((Y4).w); A[7] += (W) * bf_hi((Y4).w);

__global__ __launch_bounds__(256) void k_gather_bf16(
        const ushort* __restrict__ Y,
        const int* __restrict__ cnt,
        const int2* __restrict__ slots,
        const float* __restrict__ bias,
        float* __restrict__ out) {
    int node = blockIdx.x * 16 + (threadIdx.x >> 4);
    if (node >= N_NODES) return;
    int c = (threadIdx.x & 15) * 8;           // 8 dims per lane
    int deg = cnt[node];
    if (deg > CAP) deg = CAP;
    const int2* sp = slots + (size_t)node * CAP;

    float a0[8], a1[8];
#pragma unroll
    for (int k = 0; k < 8; ++k) { a0[k] = 0.f; a1[k] = 0.f; }

    int j = 0;
    for (; j + 3 < deg; j += 4) {
        int4 sA = *(const int4*)(sp + j);       // edges j, j+1
        int4 sB = *(const int4*)(sp + j + 2);   // edges j+2, j+3
        uint4 y0 = *(const uint4*)(Y + (size_t)sA.x * DIM + c);
        uint4 y1 = *(const uint4*)(Y + (size_t)sA.z * DIM + c);
        uint4 y2 = *(const uint4*)(Y + (size_t)sB.x * DIM + c);
        uint4 y3 = *(const uint4*)(Y + (size_t)sB.z * DIM + c);
        float w0 = __int_as_float(sA.y), w1 = __int_as_float(sA.w);
        float w2 = __int_as_float(sB.y), w3 = __int_as_float(sB.w);
        ACC8(a0, w0, y0); ACC8(a1, w1, y1);
        ACC8(a0, w2, y2); ACC8(a1, w3, y3);
    }
    for (; j < deg; ++j) {
        int2 m0 = sp[j];
        uint4 y0 = *(const uint4*)(Y + (size_t)m0.x * DIM + c);
        float w0 = __int_as_float(m0.y);
        ACC8(a0, w0, y0);
    }

    float4 bA = *(const float4*)(bias + c);
    float4 bB = *(const float4*)(bias + c + 4);
    float* op = out + (size_t)node * DIM + c;
    *(float4*)(op + 0) = make_float4(a0[0] + a1[0] + bA.x, a0[1] + a1[1] + bA.y,
                                     a0[2] + a1[2] + bA.z, a0[3] + a1[3] + bA.w);
    *(float4*)(op + 4) = make_float4(a0[4] + a1[4] + bB.x, a0[5] + a1[5] + bB.y,
                                     a0[6] + a1[6] + bB.z, a0[7] + a1[7] + bB.w);
}

// ---------------- fallback path kernels (ws too small) ----------------
__global__ void zero_ws(float4* __restrict__ p, int n4) {
    int i = blockIdx.x * blockDim.x + threadIdx.x;
    if (i < n4) p[i] = make_float4(0.f, 0.f, 0.f, 0.f);
}

__global__ __launch_bounds__(256) void scatter_edges(
        const float* __restrict__ x,
        const float* __restrict__ ew,
        const int* __restrict__ esrc,
        const int* __restrict__ edst,
        float* __restrict__ agg) {
    long long t = (long long)blockIdx.x * blockDim.x + threadIdx.x;
    int e = (int)(t >> 5);
    if (e >= N_EDGES) return;
    int d4 = ((int)t & 31) * 4;
    int s = esrc[e];
    int d = edst[e];
    float w = ew[e];
    float4 xv = *(const float4*)(x + (size_t)s * DIM + d4);
    float* ap = agg + (size_t)d * DIM + d4;
    atomicAdd(ap + 0, w * xv.x);
    atomicAdd(ap + 1, w * xv.y);
    atomicAdd(ap + 2, w * xv.z);
    atomicAdd(ap + 3, w * xv.w);
}

__global__ __launch_bounds__(256) void gemm_f32_bias(
        const float* __restrict__ A,
        const float* __restrict__ W,
        const float* __restrict__ bias,
        float* __restrict__ out) {
    __shared__ float Ws[DIM][DIM];
    int tid = threadIdx.x;
    const float4* W4 = (const float4*)W;
    float4* Ws4 = (float4*)&Ws[0][0];
#pragma unroll
    for (int i = 0; i < 16; ++i) Ws4[tid + 256 * i] = W4[tid + 256 * i];
    __syncthreads();

    int row0 = blockIdx.x * 64 + (tid >> 5) * 8;
    int cg = (tid & 31) * 4;
    float4 b = *(const float4*)(bias + cg);
    float acc[8][4];
#pragma unroll
    for (int i = 0; i < 8; ++i) {
        acc[i][0] = b.x; acc[i][1] = b.y; acc[i][2] = b.z; acc[i][3] = b.w;
    }
    int rload[8];
#pragma unroll
    for (int i = 0; i < 8; ++i) {
        int r = row0 + i;
        rload[i] = (r < N_NODES) ? r : (N_NODES - 1);
    }
    for (int kt = 0; kt < 32; ++kt) {
        float4 xr[8];
#pragma unroll
        for (int i = 0; i < 8; ++i)
            xr[i] = *(const float4*)(A + (size_t)rload[i] * DIM + kt * 4);
        float4 wr[4];
#pragma unroll
        for (int j = 0; j < 4; ++j)
            wr[j] = *(const float4*)&Ws[kt * 4 + j][cg];
#pragma unroll
        for (int i = 0; i < 8; ++i) {
            acc[i][0] += xr[i].x * wr[0].x + xr[i].y * wr[1].x + xr[i].z * wr[2].x + xr[i].w * wr[3].x;
            acc[i][1] += xr[i].x * wr[0].y + xr[i].y * wr[1].y + xr[i].z * wr[2].y + xr[i].w * wr[3].y;
            acc[i][2] += xr[i].x * wr[0].z + xr[i].y * wr[1].z + xr[i].z * wr[2].z + xr[i].w * wr[3].z;
            acc[i][3] += xr[i].x * wr[0].w + xr[i].y * wr[1].w + xr[i].z * wr[2].w + xr[i].w * wr[3].w;
        }
    }
#pragma unroll
    for (int i = 0; i < 8; ++i) {
        int row = row0 + i;
        if (row >= N_NODES) break;
        *(float4*)(out + (size_t)row * DIM + cg) =
            make_float4(acc[i][0], acc[i][1], acc[i][2], acc[i][3]);
    }
}

extern "C" void kernel_launch(void* const* d_in, const int* in_sizes, int n_in,
                              void* d_out, int out_size, void* d_ws, size_t ws_size,
                              hipStream_t stream) {
    const float* batch_x     = (const float*)d_in[0];
    const float* edge_weight = (const float*)d_in[1];
    const float* weight      = (const float*)d_in[2];
    const float* bias        = (const float*)d_in[3];
    const int*   edge_src    = (const int*)d_in[4];
    const int*   edge_dst    = (const int*)d_in[5];
    float* out = (float*)d_out;

    auto align256 = [](size_t x) { return (x + 255) & ~(size_t)255; };
    char* ws = (char*)d_ws;

    size_t oY    = 0;                                                        // 12.8 MB
    size_t oCnt  = align256(oY + (size_t)N_NODES * DIM * sizeof(ushort));    // 200 KB
    size_t oSlot = align256(oCnt + (size_t)N_NODES * sizeof(int));           // 25.6 MB
    size_t oWt   = align256(oSlot + (size_t)N_NODES * CAP * sizeof(int2));   // 32 KB
    size_t needed = oWt + (size_t)DIM * DIM * sizeof(ushort);

    if (ws_size >= needed) {
        ushort* Y    = (ushort*)(ws + oY);
        int*    cnt  = (int*)(ws + oCnt);
        int2*   slot = (int2*)(ws + oSlot);
        ushort* Wt   = (ushort*)(ws + oWt);

        // 1) prep W (transpose+bf16) and zero counters
        k_prep<<<16 + (N_NODES / 4 + 255) / 256, 256, 0, stream>>>(
            weight, Wt, (int4*)cnt);

        // 2) Y = bf16(X @ W) via MFMA (no LDS)
        gemm_mfma2<<<(N_NODES + 63) / 64, 256, 0, stream>>>(batch_x, Wt, Y);

        // 3) direct bucket fill (light kernel, full occupancy)
        k_fill_direct<<<(N_EDGES + 255) / 256, 256, 0, stream>>>(
            edge_src, edge_dst, edge_weight, cnt, slot);

        // 4) gather + bias
        k_gather_bf16<<<(N_NODES + 15) / 16, 256, 0, stream>>>(
            Y, cnt, slot, bias, out);
    } else {
        // fallback: atomic path (needs 25.6 MB)
        float* agg = (float*)d_ws;
        int n4 = N_NODES * DIM / 4;
        zero_ws<<<(n4 + 255) / 256, 256, 0, stream>>>((float4*)agg, n4);
        long long threads = (long long)N_EDGES * 32;
        scatter_edges<<<(int)((threads + 255) / 256), 256, 0, stream>>>(
            batch_x, edge_weight, edge_src, edge_dst, agg);
        gemm_f32_bias<<<(N_NODES + 63) / 64, 256, 0, stream>>>(
            agg, weight, bias, out);
    }
}

// Round 12
// 84.544 us; speedup vs baseline: 1.1267x; 1.1267x over previous
//
#include <hip/hip_runtime.h>
#include <hip/hip_bf16.h>

#define N_NODES 50000
#define N_EDGES 600000
#define DIM 128
#define CAP 64            // slots per node; P(deg>=64) ~ 1.6e-28 for Poisson(12)
#define WLDS_STRIDE 136   // 128 + 8 ushort pad: 2-way bank alias on b128 reads (free)

typedef __attribute__((ext_vector_type(8))) short bf16x8;
typedef __attribute__((ext_vector_type(4))) float floatx4;

// ---------------- prep: Wt[n][k] = bf16(W[k][n]); also zero cnt ----------------
// (verbatim from round 8, which passed post-timing)
__global__ __launch_bounds__(256) void k_prep(const float* __restrict__ W,
                                              ushort* __restrict__ Wt,
                                              int4* __restrict__ cnt4) {
    int b = blockIdx.x;
    if (b < 16) {
        int idx = (b * 256 + threadIdx.x) * 4;
        float4 v = *(const float4*)(W + idx);
        int k = idx >> 7, n = idx & 127;
        Wt[(size_t)(n + 0) * DIM + k] = __bfloat16_as_ushort(__float2bfloat16(v.x));
        Wt[(size_t)(n + 1) * DIM + k] = __bfloat16_as_ushort(__float2bfloat16(v.y));
        Wt[(size_t)(n + 2) * DIM + k] = __bfloat16_as_ushort(__float2bfloat16(v.z));
        Wt[(size_t)(n + 3) * DIM + k] = __bfloat16_as_ushort(__float2bfloat16(v.w));
    } else {
        int i = (b - 16) * 256 + threadIdx.x;
        if (i < N_NODES / 4) cnt4[i] = make_int4(0, 0, 0, 0);
    }
}

// ---------------- direct bucket fill (verbatim from round 8) ----------------
__global__ __launch_bounds__(256) void k_fill_direct(
        const int* __restrict__ esrc,
        const int* __restrict__ edst,
        const float* __restrict__ ew,
        int* __restrict__ cnt,
        int2* __restrict__ slots) {
    int e = blockIdx.x * blockDim.x + threadIdx.x;
    if (e >= N_EDGES) return;
    int d = edst[e];
    int pos = atomicAdd(&cnt[d], 1);
    if (pos < CAP)
        slots[(size_t)d * CAP + pos] = make_int2(esrc[e], __float_as_int(ew[e]));
}

// ---------------- MFMA GEMM: Y = bf16(X @ W), 64 rows/block ----------------
// Exactly the gemm path of round 9's k_fused (which passed post-timing),
// extracted standalone: LDS-staged W, X loads inside the kk loop, swapped
// operands mfma(A=Wfrag, B=Xfrag) -> lane (m,q) holds Y[wr+m][ct*16+q*4+r],
// epilogue = 8x ushort4 stores.
__global__ __launch_bounds__(256) void gemm_mfma(
        const float* __restrict__ X,
        const ushort* __restrict__ Wt,
        ushort* __restrict__ Y) {
    __shared__ ushort Wlds[DIM * WLDS_STRIDE];   // 34816 B
    int t = threadIdx.x;

#pragma unroll
    for (int i = 0; i < 8; ++i) {
        int g = t + 256 * i;
        int n = g >> 4, c = g & 15;
        *(uint4*)&Wlds[n * WLDS_STRIDE + c * 8] = ((const uint4*)Wt)[g];
    }
    __syncthreads();

    int w = t >> 6, l = t & 63;
    int wr = blockIdx.x * 64 + w * 16;
    int m = l & 15, q = l >> 4;
    int rowA = wr + m;
    if (rowA >= N_NODES) rowA = N_NODES - 1;      // clamp loads; stores guarded
    const float* xp = X + (size_t)rowA * DIM + q * 8;

    floatx4 acc[8];
#pragma unroll
    for (int ct = 0; ct < 8; ++ct)
        acc[ct] = (floatx4){0.f, 0.f, 0.f, 0.f};

    const ushort* wl = &Wlds[m * WLDS_STRIDE + q * 8];
#pragma unroll
    for (int kk = 0; kk < 4; ++kk) {
        float4 x0 = *(const float4*)(xp + kk * 32);
        float4 x1 = *(const float4*)(xp + kk * 32 + 4);
        bf16x8 xf;
        xf[0] = (short)__bfloat16_as_ushort(__float2bfloat16(x0.x));
        xf[1] = (short)__bfloat16_as_ushort(__float2bfloat16(x0.y));
        xf[2] = (short)__bfloat16_as_ushort(__float2bfloat16(x0.z));
        xf[3] = (short)__bfloat16_as_ushort(__float2bfloat16(x0.w));
        xf[4] = (short)__bfloat16_as_ushort(__float2bfloat16(x1.x));
        xf[5] = (short)__bfloat16_as_ushort(__float2bfloat16(x1.y));
        xf[6] = (short)__bfloat16_as_ushort(__float2bfloat16(x1.z));
        xf[7] = (short)__bfloat16_as_ushort(__float2bfloat16(x1.w));
#pragma unroll
        for (int ct = 0; ct < 8; ++ct) {
            bf16x8 wf = *(const bf16x8*)(wl + (size_t)(ct * 16) * WLDS_STRIDE + kk * 32);
            acc[ct] = __builtin_amdgcn_mfma_f32_16x16x32_bf16(wf, xf, acc[ct], 0, 0, 0);
        }
    }

    int row = wr + m;
    if (row < N_NODES) {
        ushort* yp = Y + (size_t)row * DIM + q * 4;
#pragma unroll
        for (int ct = 0; ct < 8; ++ct) {
            ushort4 o;
            o.x = __bfloat16_as_ushort(__float2bfloat16(acc[ct][0]));
            o.y = __bfloat16_as_ushort(__float2bfloat16(acc[ct][1]));
            o.z = __bfloat16_as_ushort(__float2bfloat16(acc[ct][2]));
            o.w = __bfloat16_as_ushort(__float2bfloat16(acc[ct][3]));
            *(ushort4*)(yp + ct * 16) = o;
        }
    }
}

// ---------------- gather (verbatim from round 8): 16 lanes/node ----------------
__device__ __forceinline__ float bf_lo(unsigned u) {
    return __uint_as_float(u << 16);
}
__device__ __forceinline__ float bf_hi(unsigned u) {
    return __uint_as_float(u & 0xFFFF0000u);
}

#define ACC8(A, W, Y4)                                        \
    A[0] += (W) * bf_lo((Y4).x); A[1] += (W) * bf_hi((Y4).x); \
    A[2] += (W) * bf_lo((Y4).y); A[3] += (W) * bf_hi((Y4).y); \
    A[4] += (W) * bf_lo((Y4).z); A[5] += (W) * bf_hi((Y4).z); \
    A[6] += (W) * bf_lo((Y4).w); A[7] += (W) * bf_hi((Y4).w);

__global__ __launch_bounds__(256) void k_gather_bf16(
        const ushort* __restrict__ Y,
        const int* __restrict__ cnt,
        const int2* __restrict__ slots,
        const float* __restrict__ bias,
        float* __restrict__ out) {
    int node = blockIdx.x * 16 + (threadIdx.x >> 4);
    if (node >= N_NODES) return;
    int c = (threadIdx.x & 15) * 8;           // 8 dims per lane
    int deg = cnt[node];
    if (deg > CAP) deg = CAP;
    const int2* sp = slots + (size_t)node * CAP;

    float a0[8], a1[8];
#pragma unroll
    for (int k = 0; k < 8; ++k) { a0[k] = 0.f; a1[k] = 0.f; }

    int j = 0;
    for (; j + 3 < deg; j += 4) {
        int4 sA = *(const int4*)(sp + j);       // edges j, j+1
        int4 sB = *(const int4*)(sp + j + 2);   // edges j+2, j+3
        uint4 y0 = *(const uint4*)(Y + (size_t)sA.x * DIM + c);
        uint4 y1 = *(const uint4*)(Y + (size_t)sA.z * DIM + c);
        uint4 y2 = *(const uint4*)(Y + (size_t)sB.x * DIM + c);
        uint4 y3 = *(const uint4*)(Y + (size_t)sB.z * DIM + c);
        float w0 = __int_as_float(sA.y), w1 = __int_as_float(sA.w);
        float w2 = __int_as_float(sB.y), w3 = __int_as_float(sB.w);
        ACC8(a0, w0, y0); ACC8(a1, w1, y1);
        ACC8(a0, w2, y2); ACC8(a1, w3, y3);
    }
    for (; j < deg; ++j) {
        int2 m0 = sp[j];
        uint4 y0 = *(const uint4*)(Y + (size_t)m0.x * DIM + c);
        float w0 = __int_as_float(m0.y);
        ACC8(a0, w0, y0);
    }

    float4 bA = *(const float4*)(bias + c);
    float4 bB = *(const float4*)(bias + c + 4);
    float* op = out + (size_t)node * DIM + c;
    *(float4*)(op + 0) = make_float4(a0[0] + a1[0] + bA.x, a0[1] + a1[1] + bA.y,
                                     a0[2] + a1[2] + bA.z, a0[3] + a1[3] + bA.w);
    *(float4*)(op + 4) = make_float4(a0[4] + a1[4] + bB.x, a0[5] + a1[5] + bB.y,
                                     a0[6] + a1[6] + bB.z, a0[7] + a1[7] + bB.w);
}

// ---------------- fallback path kernels (ws too small) ----------------
__global__ void zero_ws(float4* __restrict__ p, int n4) {
    int i = blockIdx.x * blockDim.x + threadIdx.x;
    if (i < n4) p[i] = make_float4(0.f, 0.f, 0.f, 0.f);
}

__global__ __launch_bounds__(256) void scatter_edges(
        const float* __restrict__ x,
        const float* __restrict__ ew,
        const int* __restrict__ esrc,
        const int* __restrict__ edst,
        float* __restrict__ agg) {
    long long t = (long long)blockIdx.x * blockDim.x + threadIdx.x;
    int e = (int)(t >> 5);
    if (e >= N_EDGES) return;
    int d4 = ((int)t & 31) * 4;
    int s = esrc[e];
    int d = edst[e];
    float w = ew[e];
    float4 xv = *(const float4*)(x + (size_t)s * DIM + d4);
    float* ap = agg + (size_t)d * DIM + d4;
    atomicAdd(ap + 0, w * xv.x);
    atomicAdd(ap + 1, w * xv.y);
    atomicAdd(ap + 2, w * xv.z);
    atomicAdd(ap + 3, w * xv.w);
}

__global__ __launch_bounds__(256) void gemm_f32_bias(
        const float* __restrict__ A,
        const float* __restrict__ W,
        const float* __restrict__ bias,
        float* __restrict__ out) {
    __shared__ float Ws[DIM][DIM];
    int tid = threadIdx.x;
    const float4* W4 = (const float4*)W;
    float4* Ws4 = (float4*)&Ws[0][0];
#pragma unroll
    for (int i = 0; i < 16; ++i) Ws4[tid + 256 * i] = W4[tid + 256 * i];
    __syncthreads();

    int row0 = blockIdx.x * 64 + (tid >> 5) * 8;
    int cg = (tid & 31) * 4;
    float4 b = *(const float4*)(bias + cg);
    float acc[8][4];
#pragma unroll
    for (int i = 0; i < 8; ++i) {
        acc[i][0] = b.x; acc[i][1] = b.y; acc[i][2] = b.z; acc[i][3] = b.w;
    }
    int rload[8];
#pragma unroll
    for (int i = 0; i < 8; ++i) {
        int r = row0 + i;
        rload[i] = (r < N_NODES) ? r : (N_NODES - 1);
    }
    for (int kt = 0; kt < 32; ++kt) {
        float4 xr[8];
#pragma unroll
        for (int i = 0; i < 8; ++i)
            xr[i] = *(const float4*)(A + (size_t)rload[i] * DIM + kt * 4);
        float4 wr[4];
#pragma unroll
        for (int j = 0; j < 4; ++j)
            wr[j] = *(const float4*)&Ws[kt * 4 + j][cg];
#pragma unroll
        for (int i = 0; i < 8; ++i) {
            acc[i][0] += xr[i].x * wr[0].x + xr[i].y * wr[1].x + xr[i].z * wr[2].x + xr[i].w * wr[3].x;
            acc[i][1] += xr[i].x * wr[0].y + xr[i].y * wr[1].y + xr[i].z * wr[2].y + xr[i].w * wr[3].y;
            acc[i][2] += xr[i].x * wr[0].z + xr[i].y * wr[1].z + xr[i].z * wr[2].z + xr[i].w * wr[3].z;
            acc[i][3] += xr[i].x * wr[0].w + xr[i].y * wr[1].w + xr[i].z * wr[2].w + xr[i].w * wr[3].w;
        }
    }
#pragma unroll
    for (int i = 0; i < 8; ++i) {
        int row = row0 + i;
        if (row >= N_NODES) break;
        *(float4*)(out + (size_t)row * DIM + cg) =
            make_float4(acc[i][0], acc[i][1], acc[i][2], acc[i][3]);
    }
}

extern "C" void kernel_launch(void* const* d_in, const int* in_sizes, int n_in,
                              void* d_out, int out_size, void* d_ws, size_t ws_size,
                              hipStream_t stream) {
    const float* batch_x     = (const float*)d_in[0];
    const float* edge_weight = (const float*)d_in[1];
    const float* weight      = (const float*)d_in[2];
    const float* bias        = (const float*)d_in[3];
    const int*   edge_src    = (const int*)d_in[4];
    const int*   edge_dst    = (const int*)d_in[5];
    float* out = (float*)d_out;

    auto align256 = [](size_t x) { return (x + 255) & ~(size_t)255; };
    char* ws = (char*)d_ws;

    size_t oY    = 0;                                                        // 12.8 MB
    size_t oCnt  = align256(oY + (size_t)N_NODES * DIM * sizeof(ushort));    // 200 KB
    size_t oSlot = align256(oCnt + (size_t)N_NODES * sizeof(int));           // 25.6 MB
    size_t oWt   = align256(oSlot + (size_t)N_NODES * CAP * sizeof(int2));   // 32 KB
    size_t needed = oWt + (size_t)DIM * DIM * sizeof(ushort);

    if (ws_size >= needed) {
        ushort* Y    = (ushort*)(ws + oY);
        int*    cnt  = (int*)(ws + oCnt);
        int2*   slot = (int2*)(ws + oSlot);
        ushort* Wt   = (ushort*)(ws + oWt);

        // 1) prep W (transpose+bf16) and zero counters
        k_prep<<<16 + (N_NODES / 4 + 255) / 256, 256, 0, stream>>>(
            weight, Wt, (int4*)cnt);

        // 2) direct bucket fill
        k_fill_direct<<<(N_EDGES + 255) / 256, 256, 0, stream>>>(
            edge_src, edge_dst, edge_weight, cnt, slot);

        // 3) Y = bf16(X @ W) via MFMA (LDS-staged W, swapped-operand epilogue)
        gemm_mfma<<<(N_NODES + 63) / 64, 256, 0, stream>>>(batch_x, Wt, Y);

        // 4) gather + bias
        k_gather_bf16<<<(N_NODES + 15) / 16, 256, 0, stream>>>(
            Y, cnt, slot, bias, out);
    } else {
        // fallback: atomic path (needs 25.6 MB)
        float* agg = (float*)d_ws;
        int n4 = N_NODES * DIM / 4;
        zero_ws<<<(n4 + 255) / 256, 256, 0, stream>>>((float4*)agg, n4);
        long long threads = (long long)N_EDGES * 32;
        scatter_edges<<<(int)((threads + 255) / 256), 256, 0, stream>>>(
            batch_x, edge_weight, edge_src, edge_dst, agg);
        gemm_f32_bias<<<(N_NODES + 63) / 64, 256, 0, stream>>>(
            agg, weight, bias, out);
    }
}